// Round 2
// baseline (1109.115 us; speedup 1.0000x reference)
//
#include <hip/hip_runtime.h>
#include <math.h>

#define B_  32
#define N_  256
#define K_  8
#define HW_ 196
#define C_  1000
#define D_  50176            // N_*HW_
#define WK_ 12845056         // N_*N_*HW_ per k

// ws float offsets
#define WS_AH  50176
#define WS_DR  100352

// dim_red tiling
#define CH_  784             // floats of d per block chunk (= 4*196 = 49 cache lines)
#define NPH_ 28              // phases per chunk
#define SW_  28              // floats of d per phase

__device__ __forceinline__ void gload16(const float* g, float* l) {
  __builtin_amdgcn_global_load_lds((const __attribute__((address_space(1))) void*)g,
                                   (__attribute__((address_space(3))) void*)l, 16, 0, 0);
}

// ---------------- kernel 1: logits + softmax + loss + zero-dr (one block per b) ----------------
__global__ __launch_bounds__(256) void k_front(const float* __restrict__ x,
                                               const float* __restrict__ cw,
                                               float* __restrict__ ws,
                                               float* __restrict__ out) {
  const int b = blockIdx.x, t = threadIdx.x;
  __shared__ float cwl[K_][N_];
  __shared__ float AH[K_][HW_ + 4];
  __shared__ float red[256];
#pragma unroll
  for (int i = 0; i < 8; ++i) {
    const int idx = i*256 + t;
    cwl[idx >> 8][idx & 255] = cw[idx];
    ws[WS_DR + b*(K_*N_) + idx] = 0.f;   // zero dim_red accumulator
  }
  __syncthreads();
  if (t < HW_) {
    float acc[K_];
#pragma unroll
    for (int k = 0; k < K_; ++k) acc[k] = 0.f;
    const float* xb = x + (size_t)b*D_ + t;
#pragma unroll 4
    for (int n = 0; n < N_; ++n) {
      const float xv = xb[(size_t)n*HW_];
#pragma unroll
      for (int k = 0; k < K_; ++k) acc[k] = fmaf(xv, cwl[k][n], acc[k]);
    }
    float m = acc[0];
#pragma unroll
    for (int k = 1; k < K_; ++k) m = fmaxf(m, acc[k]);
    float s = 0.f;
#pragma unroll
    for (int k = 0; k < K_; ++k) { acc[k] = __expf(acc[k] - m); s += acc[k]; }
    const float inv = 1.f / s;
#pragma unroll
    for (int k = 0; k < K_; ++k) {
      const float a = acc[k] * inv;
      AH[k][t] = a;
      ws[WS_AH + (b*K_ + k)*HW_ + t] = a;
    }
  }
  __syncthreads();
  float l = 0.f;
  if (t < HW_) {                       // G[w,v] contribution
    const int w = t / 14, v2 = t % 14;
    float g = 0.f;
#pragma unroll
    for (int k = 0; k < K_; ++k)
#pragma unroll
      for (int h = 0; h < 14; ++h)
        g = fmaf(AH[k][h*14 + w], AH[k][h*14 + v2], g);
    l = g * g;
  }
  if (t < 112) {                       // loss2
    const int k2 = t / 14, w = t % 14;
    float s = 0.f;
#pragma unroll
    for (int h = 0; h < 14; ++h) s += AH[k2][h*14 + w];
    l -= s * s;
  }
  red[t] = l;
  __syncthreads();
  for (int s2 = 128; s2 > 0; s2 >>= 1) { if (t < s2) red[t] += red[t + s2]; __syncthreads(); }
  if (t == 0) out[256256 + b] = red[0];
}

// ---------------- kernel 2: dim_red (411 MB of dimred_w, double-buffered gload_lds) ----------------
// grid (64,8): 64 chunks of 784 d per k. 128 threads, per-thread 8b x 8m fp32 tile.
__global__ __launch_bounds__(128, 1) void k_dimred(const float* __restrict__ x,
                                                   const float* __restrict__ ah,
                                                   const float* __restrict__ dw,
                                                   float* __restrict__ dr) {
  const int chunk = blockIdx.x, k = blockIdx.y;
  const int t = threadIdx.x;
  const int lane = t & 63, wv = t >> 6;
  const int tb = lane >> 4;              // 0..3  -> b = tb + 4i
  const int tm = (lane & 15) + wv * 16;  // 0..31 -> m = tm + 32j

  __shared__ float Wl[2][256 * SW_];     // [buf][m*28 + c] flat, 112B rows (2-way banks: free)
  __shared__ float Al[2][32 * SW_];      // [buf][b*28 + c] flat

  const float* Wk = dw + (size_t)k * WK_;
  const int d0 = chunk * CH_;

  // W-stage slots: j = i*128 + t -> (m = j/7, c = j%7), phase-invariant float offsets
  int woff[14];
#pragma unroll
  for (int i = 0; i < 14; ++i) {
    const int j = i*128 + t;
    woff[i] = (j/7)*D_ + (j%7)*4;
  }
  // A-stage slots: e in {t, t+128 (if t<96)}
  const int e0 = t, e1 = t + 128;
  const int b0 = e0/7, c0 = e0%7;
  const int b1 = e1/7, c1 = e1%7;
  const bool has1 = (t < 96);
  int hw0 = c0*4, hw1 = c1*4;            // d0 % 196 == 0 (784 = 4*196)
  const float* xb0 = x + (size_t)b0*D_ + d0 + c0*4;
  const float* ab0 = ah + (b0*K_ + k)*HW_;
  const float* xb1 = x + (size_t)b1*D_ + d0 + c1*4;
  const float* ab1 = ah + (b1*K_ + k)*HW_;

  float acc[8][8];
#pragma unroll
  for (int i = 0; i < 8; ++i)
#pragma unroll
    for (int j = 0; j < 8; ++j) acc[i][j] = 0.f;

  // ---- prologue: stage phase 0 ----
  {
    float4 xv0 = *(const float4*)xb0;
    float4 a40 = *(const float4*)(ab0 + hw0);
    float4 xv1, a41;
    if (has1) { xv1 = *(const float4*)xb1; a41 = *(const float4*)(ab1 + hw1); }
    const float* wb = Wk + d0;
#pragma unroll
    for (int i = 0; i < 14; ++i) gload16(wb + woff[i], &Wl[0][i*512 + wv*256]);
    float4 av;
    av.x = xv0.x*a40.x; av.y = xv0.y*a40.y; av.z = xv0.z*a40.z; av.w = xv0.w*a40.w;
    *(float4*)&Al[0][4*e0] = av;
    if (has1) {
      av.x = xv1.x*a41.x; av.y = xv1.y*a41.y; av.z = xv1.z*a41.z; av.w = xv1.w*a41.w;
      *(float4*)&Al[0][4*e1] = av;
    }
    hw0 += SW_; if (hw0 >= HW_) hw0 -= HW_;
    hw1 += SW_; if (hw1 >= HW_) hw1 -= HW_;
  }
  __syncthreads();

  // ---- main loop: prefetch(ph+1) || compute(ph), one barrier per phase ----
#pragma unroll 2
  for (int ph = 0; ph < NPH_; ++ph) {
    const int cur = ph & 1, nxt = cur ^ 1;
    const bool pf = (ph + 1 < NPH_);
    float4 xv0, a40, xv1, a41;
    if (pf) {
      const int off = (ph + 1) * SW_;
      xv0 = *(const float4*)(xb0 + off);
      a40 = *(const float4*)(ab0 + hw0);
      if (has1) { xv1 = *(const float4*)(xb1 + off); a41 = *(const float4*)(ab1 + hw1); }
      const float* wb = Wk + d0 + off;
#pragma unroll
      for (int i = 0; i < 14; ++i) gload16(wb + woff[i], &Wl[nxt][i*512 + wv*256]);
    }
    const float* Wc = &Wl[cur][tm * SW_];
    const float* Ac = &Al[cur][tb * SW_];
#pragma unroll
    for (int q = 0; q < 7; ++q) {
      const int dq = q*4;
      float4 a4[8], w4[8];
#pragma unroll
      for (int i = 0; i < 8; ++i) a4[i] = *(const float4*)(Ac + i*(4*SW_) + dq);
#pragma unroll
      for (int j = 0; j < 8; ++j) w4[j] = *(const float4*)(Wc + j*(32*SW_) + dq);
#pragma unroll
      for (int i = 0; i < 8; ++i)
#pragma unroll
        for (int j = 0; j < 8; ++j) {
          acc[i][j] = fmaf(a4[i].x, w4[j].x, acc[i][j]);
          acc[i][j] = fmaf(a4[i].y, w4[j].y, acc[i][j]);
          acc[i][j] = fmaf(a4[i].z, w4[j].z, acc[i][j]);
          acc[i][j] = fmaf(a4[i].w, w4[j].w, acc[i][j]);
        }
    }
    if (pf) {
      float4 av;
      av.x = xv0.x*a40.x; av.y = xv0.y*a40.y; av.z = xv0.z*a40.z; av.w = xv0.w*a40.w;
      *(float4*)&Al[nxt][4*e0] = av;
      if (has1) {
        av.x = xv1.x*a41.x; av.y = xv1.y*a41.y; av.z = xv1.z*a41.z; av.w = xv1.w*a41.w;
        *(float4*)&Al[nxt][4*e1] = av;
      }
      hw0 += SW_; if (hw0 >= HW_) hw0 -= HW_;
      hw1 += SW_; if (hw1 >= HW_) hw1 -= HW_;
    }
    __syncthreads();
  }

#pragma unroll
  for (int i = 0; i < 8; ++i) {
    const int bb = tb + 4*i;
#pragma unroll
    for (int j = 0; j < 8; ++j) {
      const int mm = tm + 32*j;
      atomicAdd(&dr[(bb*K_ + k)*N_ + mm], acc[i][j]);
    }
  }
}

// ---------------- kernel 3: hyp = dr@Wo^T + b ; conf = tanh(dr@Wg + b) ----------------
__global__ __launch_bounds__(256) void k_out(const float* __restrict__ dr,
                                             const float* __restrict__ db,
                                             const float* __restrict__ Wo,
                                             const float* __restrict__ Wob,
                                             const float* __restrict__ Wg,
                                             const float* __restrict__ Wgb,
                                             float* __restrict__ out) {
  const int ct = blockIdx.x, k = blockIdx.y;
  const int t = threadIdx.x;
  __shared__ float Wl[32][257];
  __shared__ float dl[256][36];
#pragma unroll
  for (int i = 0; i < 32; ++i) {
    const int e = i*256 + t;
    const int row = e >> 8, col = e & 255;
    const int c = ct*32 + row;
    Wl[row][col] = (c < C_) ? Wo[((size_t)(k*C_ + c))*N_ + col] : 0.f;
  }
#pragma unroll
  for (int i = 0; i < 32; ++i) {
    const int e = i*256 + t;
    const int n = e & 255, b = e >> 8;
    dl[n][b] = dr[(b*K_ + k)*N_ + n] + db[k*N_ + n];
  }
  __syncthreads();
  const int tc = t & 31, tg = t >> 5;
  const int c = ct*32 + tc;
  float a0=0.f, a1=0.f, a2=0.f, a3=0.f;
#pragma unroll 8
  for (int n = 0; n < N_; ++n) {
    const float wvv = Wl[tc][n];
    const float4 dv = *(const float4*)&dl[n][tg*4];
    a0 = fmaf(wvv, dv.x, a0);
    a1 = fmaf(wvv, dv.y, a1);
    a2 = fmaf(wvv, dv.z, a2);
    a3 = fmaf(wvv, dv.w, a3);
  }
  if (c < C_) {
    const float bias = Wob[k*C_ + c];
    out[((size_t)(tg*4 + 0)*K_ + k)*C_ + c] = a0 + bias;
    out[((size_t)(tg*4 + 1)*K_ + k)*C_ + c] = a1 + bias;
    out[((size_t)(tg*4 + 2)*K_ + k)*C_ + c] = a2 + bias;
    out[((size_t)(tg*4 + 3)*K_ + k)*C_ + c] = a3 + bias;
  }
  if (ct == 0 && t < B_) {
    float s = Wgb[k];
    for (int n = 0; n < N_; ++n) s = fmaf(dl[n][t], Wg[k*N_ + n], s);
    out[256000 + t*K_ + k] = tanhf(s);
  }
}

extern "C" void kernel_launch(void* const* d_in, const int* in_sizes, int n_in,
                              void* d_out, int out_size, void* d_ws, size_t ws_size,
                              hipStream_t stream) {
  const float* x   = (const float*)d_in[0];
  const float* cw  = (const float*)d_in[1];
  const float* dw  = (const float*)d_in[2];
  const float* db  = (const float*)d_in[3];
  const float* Wo  = (const float*)d_in[4];
  const float* Wob = (const float*)d_in[5];
  const float* Wg  = (const float*)d_in[6];
  const float* Wgb = (const float*)d_in[7];
  float* out = (float*)d_out;
  float* ws  = (float*)d_ws;

  k_front<<<32, 256, 0, stream>>>(x, cw, ws, out);
  k_dimred<<<dim3(64, 8), 128, 0, stream>>>(x, ws + WS_AH, dw, ws + WS_DR);
  k_out<<<dim3(32, 8), 256, 0, stream>>>(ws + WS_DR, db, Wo, Wob, Wg, Wgb, out);
}

// Round 3
// 222.149 us; speedup vs baseline: 4.9927x; 4.9927x over previous
//
#include <hip/hip_runtime.h>
#include <math.h>

#define B_  32
#define N_  256
#define K_  8
#define HW_ 196
#define C_  1000
#define D_  50176            // N_*HW_
#define WK_ 12845056         // N_*N_*HW_ per k

// ws float offsets
#define WS_AH  50176
#define WS_DR  100352

// dim_red tiling: grid (128 chunks, 8 k), 4 blocks/CU exactly
#define CH_  392             // floats of d per chunk (= 2*196)
#define NPH_ 14              // phases per chunk
#define SW_  28              // floats of d per phase (112B rows: 2-way banks = free)

__device__ __forceinline__ void gload16(const float* g, float* l) {
  __builtin_amdgcn_global_load_lds((const __attribute__((address_space(1))) void*)g,
                                   (__attribute__((address_space(3))) void*)l, 16, 0, 0);
}

// ---------------- kernel 1: logits + softmax + loss + zero-dr ----------------
__global__ __launch_bounds__(256) void k_front(const float* __restrict__ x,
                                               const float* __restrict__ cw,
                                               float* __restrict__ ws,
                                               float* __restrict__ out) {
  const int b = blockIdx.x, t = threadIdx.x;
  __shared__ float cwl[K_][N_];
  __shared__ float AH[K_][HW_ + 4];
  __shared__ float red[256];
#pragma unroll
  for (int i = 0; i < 8; ++i) {
    const int idx = i*256 + t;
    cwl[idx >> 8][idx & 255] = cw[idx];
    ws[WS_DR + b*(K_*N_) + idx] = 0.f;   // zero dim_red accumulator
  }
  __syncthreads();
  if (t < HW_) {
    float acc[K_];
#pragma unroll
    for (int k = 0; k < K_; ++k) acc[k] = 0.f;
    const float* xb = x + (size_t)b*D_ + t;
#pragma unroll 4
    for (int n = 0; n < N_; ++n) {
      const float xv = xb[(size_t)n*HW_];
#pragma unroll
      for (int k = 0; k < K_; ++k) acc[k] = fmaf(xv, cwl[k][n], acc[k]);
    }
    float m = acc[0];
#pragma unroll
    for (int k = 1; k < K_; ++k) m = fmaxf(m, acc[k]);
    float s = 0.f;
#pragma unroll
    for (int k = 0; k < K_; ++k) { acc[k] = __expf(acc[k] - m); s += acc[k]; }
    const float inv = 1.f / s;
#pragma unroll
    for (int k = 0; k < K_; ++k) {
      const float a = acc[k] * inv;
      AH[k][t] = a;
      ws[WS_AH + (b*K_ + k)*HW_ + t] = a;
    }
  }
  __syncthreads();
  float l = 0.f;
  if (t < HW_) {                       // G[w,v] contribution
    const int w = t / 14, v2 = t % 14;
    float g = 0.f;
#pragma unroll
    for (int k = 0; k < K_; ++k)
#pragma unroll
      for (int h = 0; h < 14; ++h)
        g = fmaf(AH[k][h*14 + w], AH[k][h*14 + v2], g);
    l = g * g;
  }
  if (t < 112) {                       // loss2
    const int k2 = t / 14, w = t % 14;
    float s = 0.f;
#pragma unroll
    for (int h = 0; h < 14; ++h) s += AH[k2][h*14 + w];
    l -= s * s;
  }
  red[t] = l;
  __syncthreads();
  for (int s2 = 128; s2 > 0; s2 >>= 1) { if (t < s2) red[t] += red[t + s2]; __syncthreads(); }
  if (t == 0) out[256256 + b] = red[0];
}

// ---------------- kernel 2: dim_red (411 MB of dimred_w) ----------------
// Single-buffer 2-barrier m97 structure: gload_lds W staging, 4 blocks/CU TLP overlap.
// 128 threads, per-thread 8b x 8m fp32 tile.
__global__ __launch_bounds__(128, 2) void k_dimred(const float* __restrict__ x,
                                                   const float* __restrict__ ah,
                                                   const float* __restrict__ dw,
                                                   float* __restrict__ dr) {
  const int chunk = blockIdx.x, k = blockIdx.y;
  const int t = threadIdx.x;
  const int lane = t & 63, wv = t >> 6;
  const int tb = lane >> 4;              // 0..3  -> b = tb + 4i
  const int tm = (lane & 15) + wv * 16;  // 0..31 -> m = tm + 32j

  __shared__ float Wl[256 * SW_];        // [m*28 + c], 112B rows
  __shared__ float Al[32 * SW_];         // [b*28 + c]

  const float* Wk = dw + (size_t)k * WK_;
  const int d0 = chunk * CH_;            // multiple of 196

  // W-stage slots: j = i*128 + t -> (m = j/7, c = j%7); offsets phase-invariant
  int woff[14];
#pragma unroll
  for (int i = 0; i < 14; ++i) {
    const int j = i*128 + t;
    woff[i] = (j/7)*D_ + (j%7)*4;
  }
  const int ldsbase = wv * 256;          // wave-uniform float offset step per i: 512

  // A-stage slots: e0 = t; e1 = t+128 (if t<96)
  const int e0 = t, e1 = t + 128;
  const int b0 = e0/7, c0 = e0%7;
  const int b1 = e1/7, c1 = e1%7;
  const bool has1 = (t < 96);
  int hw0 = c0*4, hw1 = c1*4;            // rotate +28 mod 196, never straddles
  const float* xb0 = x + (size_t)b0*D_ + d0 + c0*4;
  const float* ab0 = ah + (b0*K_ + k)*HW_;
  const float* xb1 = x + (size_t)b1*D_ + d0 + c1*4;
  const float* ab1 = ah + (b1*K_ + k)*HW_;

  float acc[8][8];
#pragma unroll
  for (int i = 0; i < 8; ++i)
#pragma unroll
    for (int j = 0; j < 8; ++j) acc[i][j] = 0.f;

  for (int ph = 0; ph < NPH_; ++ph) {
    // ---- stage W (async, no VGPR) ----
    const float* wb = Wk + d0 + ph*SW_;
#pragma unroll
    for (int i = 0; i < 14; ++i) gload16(wb + woff[i], &Wl[i*512 + ldsbase]);
    // ---- stage A = x * ah ----
    {
      const float4 xv = *(const float4*)(xb0 + ph*SW_);
      const float4 av = *(const float4*)(ab0 + hw0);
      float4 r;
      r.x = xv.x*av.x; r.y = xv.y*av.y; r.z = xv.z*av.z; r.w = xv.w*av.w;
      *(float4*)&Al[4*e0] = r;
    }
    if (has1) {
      const float4 xv = *(const float4*)(xb1 + ph*SW_);
      const float4 av = *(const float4*)(ab1 + hw1);
      float4 r;
      r.x = xv.x*av.x; r.y = xv.y*av.y; r.z = xv.z*av.z; r.w = xv.w*av.w;
      *(float4*)&Al[4*e1] = r;
    }
    hw0 += SW_; if (hw0 >= HW_) hw0 -= HW_;
    hw1 += SW_; if (hw1 >= HW_) hw1 -= HW_;
    __syncthreads();                      // vmcnt(0): W + A ready

    // ---- compute ----
    const float* Wc = &Wl[tm * SW_];
    const float* Ac = &Al[tb * SW_];
    for (int q = 0; q < 7; ++q) {
      const int dq = q*4;
      float4 a4[8], w4[8];
#pragma unroll
      for (int i = 0; i < 8; ++i) a4[i] = *(const float4*)(Ac + i*(4*SW_) + dq);
#pragma unroll
      for (int j = 0; j < 8; ++j) w4[j] = *(const float4*)(Wc + j*(32*SW_) + dq);
#pragma unroll
      for (int i = 0; i < 8; ++i)
#pragma unroll
        for (int j = 0; j < 8; ++j) {
          acc[i][j] = fmaf(a4[i].x, w4[j].x, acc[i][j]);
          acc[i][j] = fmaf(a4[i].y, w4[j].y, acc[i][j]);
          acc[i][j] = fmaf(a4[i].z, w4[j].z, acc[i][j]);
          acc[i][j] = fmaf(a4[i].w, w4[j].w, acc[i][j]);
        }
    }
    __syncthreads();                      // LDS free for next stage
  }

#pragma unroll
  for (int i = 0; i < 8; ++i) {
    const int bb = tb + 4*i;
#pragma unroll
    for (int j = 0; j < 8; ++j) {
      const int mm = tm + 32*j;
      atomicAdd(&dr[(bb*K_ + k)*N_ + mm], acc[i][j]);
    }
  }
}

// ---------------- kernel 3: hyp = dr@Wo^T + b ; conf = tanh(dr@Wg + b) ----------------
__global__ __launch_bounds__(256) void k_out(const float* __restrict__ dr,
                                             const float* __restrict__ db,
                                             const float* __restrict__ Wo,
                                             const float* __restrict__ Wob,
                                             const float* __restrict__ Wg,
                                             const float* __restrict__ Wgb,
                                             float* __restrict__ out) {
  const int ct = blockIdx.x, k = blockIdx.y;
  const int t = threadIdx.x;
  __shared__ float Wl[32][257];
  __shared__ float dl[256][36];
#pragma unroll
  for (int i = 0; i < 32; ++i) {
    const int e = i*256 + t;
    const int row = e >> 8, col = e & 255;
    const int c = ct*32 + row;
    Wl[row][col] = (c < C_) ? Wo[((size_t)(k*C_ + c))*N_ + col] : 0.f;
  }
#pragma unroll
  for (int i = 0; i < 32; ++i) {
    const int e = i*256 + t;
    const int n = e & 255, b = e >> 8;
    dl[n][b] = dr[(b*K_ + k)*N_ + n] + db[k*N_ + n];
  }
  __syncthreads();
  const int tc = t & 31, tg = t >> 5;
  const int c = ct*32 + tc;
  float a0=0.f, a1=0.f, a2=0.f, a3=0.f;
#pragma unroll 8
  for (int n = 0; n < N_; ++n) {
    const float wvv = Wl[tc][n];
    const float4 dv = *(const float4*)&dl[n][tg*4];
    a0 = fmaf(wvv, dv.x, a0);
    a1 = fmaf(wvv, dv.y, a1);
    a2 = fmaf(wvv, dv.z, a2);
    a3 = fmaf(wvv, dv.w, a3);
  }
  if (c < C_) {
    const float bias = Wob[k*C_ + c];
    out[((size_t)(tg*4 + 0)*K_ + k)*C_ + c] = a0 + bias;
    out[((size_t)(tg*4 + 1)*K_ + k)*C_ + c] = a1 + bias;
    out[((size_t)(tg*4 + 2)*K_ + k)*C_ + c] = a2 + bias;
    out[((size_t)(tg*4 + 3)*K_ + k)*C_ + c] = a3 + bias;
  }
  if (ct == 0 && t < B_) {
    float s = Wgb[k];
    for (int n = 0; n < N_; ++n) s = fmaf(dl[n][t], Wg[k*N_ + n], s);
    out[256000 + t*K_ + k] = tanhf(s);
  }
}

extern "C" void kernel_launch(void* const* d_in, const int* in_sizes, int n_in,
                              void* d_out, int out_size, void* d_ws, size_t ws_size,
                              hipStream_t stream) {
  const float* x   = (const float*)d_in[0];
  const float* cw  = (const float*)d_in[1];
  const float* dw  = (const float*)d_in[2];
  const float* db  = (const float*)d_in[3];
  const float* Wo  = (const float*)d_in[4];
  const float* Wob = (const float*)d_in[5];
  const float* Wg  = (const float*)d_in[6];
  const float* Wgb = (const float*)d_in[7];
  float* out = (float*)d_out;
  float* ws  = (float*)d_ws;

  k_front<<<32, 256, 0, stream>>>(x, cw, ws, out);
  k_dimred<<<dim3(128, 8), 128, 0, stream>>>(x, ws + WS_AH, dw, ws + WS_DR);
  k_out<<<dim3(32, 8), 256, 0, stream>>>(ws + WS_DR, db, Wo, Wob, Wg, Wgb, out);
}